// Round 4
// baseline (13893.600 us; speedup 1.0000x reference)
//
#include <hip/hip_runtime.h>
#include <hip/hip_fp16.h>

#define Tn 4096
#define Bn 128
#define Hn 128
#define G3 384

typedef unsigned short u16;
typedef unsigned int u32;

__device__ __forceinline__ float sigm(float v) { return 1.f / (1.f + __expf(-v)); }
__device__ __forceinline__ float tanh_fast(float v) {
  v = fminf(fmaxf(v, -15.f), 15.f);
  float e = __expf(-2.f * v);
  return (1.f - e) / (1.f + e);
}
__device__ __forceinline__ u16 f2h(float f) { return __half_as_ushort(__float2half(f)); }
__device__ __forceinline__ float h2f(u16 u) { return __half2float(__ushort_as_half(u)); }

// 32 named float4 weight registers. WPIN makes each value the result of an
// opaque asm, so the compiler can neither rematerialize the load inside the
// loop nor spill-and-reload it cheaply — forces true register residency.
#define REP32(M) M(0) M(1) M(2) M(3) M(4) M(5) M(6) M(7) M(8) M(9) M(10) M(11) \
  M(12) M(13) M(14) M(15) M(16) M(17) M(18) M(19) M(20) M(21) M(22) M(23) \
  M(24) M(25) M(26) M(27) M(28) M(29) M(30) M(31)
#define WDECL(i) float4 w##i;
#define WLOAD(i) w##i = make_float4(Wcol[(4*i+0)*G3], Wcol[(4*i+1)*G3], \
                                    Wcol[(4*i+2)*G3], Wcol[(4*i+3)*G3]);
#define WPIN(i) asm volatile("" : "+v"(w##i.x), "+v"(w##i.y), "+v"(w##i.z), "+v"(w##i.w));
#define WFMA(i) { float4 hv = h4[i]; \
  a0 = fmaf(hv.x, w##i.x, a0); a1 = fmaf(hv.y, w##i.y, a1); \
  a2 = fmaf(hv.z, w##i.z, a2); a3 = fmaf(hv.w, w##i.w, a3); }

// ---------------- encoder: reverse GRU, one WG per batch row ----------------
// Processes global steps [t0, t0+Tc); persists h state in enc_h.
__global__ __launch_bounds__(384, 1) void enc_kernel(
    const float* __restrict__ x, const float* __restrict__ Wi_e,
    const float* __restrict__ Wh_e, const float* __restrict__ bi_e,
    const float* __restrict__ bhn_e, u16* __restrict__ hx,
    float* __restrict__ enc_h, int t0, int Tc)
{
  const int j = threadIdx.x;
  const int b = blockIdx.x;
  __shared__ __align__(16) float h[Hn];
  __shared__ float g2[512];
  const float* Wcol = Wh_e + j;
  REP32(WDECL)
  REP32(WLOAD)
  REP32(WPIN)
  float wie = Wi_e[j];
  float bie = bi_e[j];
  float bhn = 0.f;
  if (j < Hn) {
    bhn = bhn_e[j];
    h[j] = (t0 == 0) ? 0.f : enc_h[(long)b * Hn + j];
  }
  asm volatile("" : "+v"(wie), "+v"(bie), "+v"(bhn));
  __syncthreads();
  const float* xrow = x + (long)b * Tn;
  u16* hxrow = hx + (long)b * Tc * Hn;
  float xt = xrow[Tn - 1 - t0];
  for (int tt = 0; tt < Tc; ++tt) {
    const int t = t0 + tt;
    const int tn = (t + 1 < Tn) ? (t + 1) : (Tn - 1);
    float xnext = xrow[Tn - 1 - tn];  // prefetch one step ahead
    float a0 = 0.f, a1 = 0.f, a2 = 0.f, a3 = 0.f;
    const float4* h4 = (const float4*)h;
    REP32(WFMA)
    float gh = (a0 + a1) + (a2 + a3);
    float gi = fmaf(xt, wie, bie);
    if (j < 256) g2[j] = gh + gi;          // r,z complete pre-activations
    else { g2[j] = gh; g2[j + 128] = gi; } // hn raw, inn raw
    __syncthreads();
    if (j < Hn) {
      float r = sigm(g2[j]);
      float z = sigm(g2[128 + j]);
      float n = tanh_fast(g2[384 + j] + r * (g2[256 + j] + bhn));
      float hn = (1.f - z) * n + z * h[j];
      h[j] = hn;
      hxrow[(long)tt * Hn + j] = f2h(hn);
    }
    xt = xnext;
    __syncthreads();
  }
  if (j < Hn) enc_h[(long)b * Hn + j] = h[j];
}

// ------- GEMM: gi_pre[row,:] = hx[row,:] @ Wi_d[1:,:] + bi_d  (fp32 acc) -------
__global__ __launch_bounds__(256) void gemm_gi(
    const u16* __restrict__ A, const float* __restrict__ Wi_d,
    const float* __restrict__ bi_d, u16* __restrict__ C)
{
  __shared__ __align__(16) float As[16][64];  // [k][m]
  __shared__ __align__(16) float Ws[16][64];  // [k][n]
  const int tid = threadIdx.x;
  const long m0 = (long)blockIdx.x * 64;
  const int n0 = blockIdx.y * 64;
  const int tx = tid & 15, ty = tid >> 4;
  const int am = tid >> 2, ak = (tid & 3) * 4;
  const int wk = tid >> 4, wn = (tid & 15) * 4;
  float acc[4][4] = {};
  for (int k0 = 0; k0 < Hn; k0 += 16) {
    uint2 a2v = *(const uint2*)(A + (m0 + am) * Hn + k0 + ak);
    float4 w4 = *(const float4*)(Wi_d + (long)(1 + k0 + wk) * G3 + n0 + wn);
    __syncthreads();
    As[ak + 0][am] = h2f((u16)(a2v.x & 0xffffu));
    As[ak + 1][am] = h2f((u16)(a2v.x >> 16));
    As[ak + 2][am] = h2f((u16)(a2v.y & 0xffffu));
    As[ak + 3][am] = h2f((u16)(a2v.y >> 16));
    *(float4*)&Ws[wk][wn] = w4;
    __syncthreads();
#pragma unroll
    for (int kk = 0; kk < 16; ++kk) {
      float4 av = *(const float4*)&As[kk][ty * 4];
      float4 wv = *(const float4*)&Ws[kk][tx * 4];
      float ar[4] = {av.x, av.y, av.z, av.w};
      float wr[4] = {wv.x, wv.y, wv.z, wv.w};
#pragma unroll
      for (int i = 0; i < 4; ++i)
#pragma unroll
        for (int jj = 0; jj < 4; ++jj) acc[i][jj] = fmaf(ar[i], wr[jj], acc[i][jj]);
    }
  }
  const float4 bb = *(const float4*)(bi_d + n0 + tx * 4);
  const float br[4] = {bb.x, bb.y, bb.z, bb.w};
#pragma unroll
  for (int i = 0; i < 4; ++i) {
    long row = m0 + ty * 4 + i;
    u32 lo = (u32)f2h(acc[i][0] + br[0]) | ((u32)f2h(acc[i][1] + br[1]) << 16);
    u32 hi = (u32)f2h(acc[i][2] + br[2]) | ((u32)f2h(acc[i][3] + br[3]) << 16);
    uint2 o; o.x = lo; o.y = hi;
    *(uint2*)(C + row * G3 + n0 + tx * 4) = o;
  }
}

// -------- decoder: autoregressive GRU + heads + mixture-logistic coupling --------
// 3 barriers/step: pred term is folded in at the gate phase, not the matvec.
__global__ __launch_bounds__(384, 1) void dec_kernel(
    const float* __restrict__ eps, const float* __restrict__ Wi_d,
    const float* __restrict__ Wh_d, const float* __restrict__ bhn_d,
    const float* __restrict__ W_shift, const float* __restrict__ b_shift,
    const float* __restrict__ W_lsc, const float* __restrict__ b_lsc,
    const float* __restrict__ W_pi, const float* __restrict__ b_pi,
    const float* __restrict__ W_mu, const float* __restrict__ b_mu,
    const float* __restrict__ W_ls, const float* __restrict__ b_ls,
    const u16* __restrict__ gi_pre, float* __restrict__ out,
    float* __restrict__ dec_h, float* __restrict__ dec_pred, int t0, int Tc)
{
  const int j = threadIdx.x;
  const int b = blockIdx.x;
  __shared__ __align__(16) float h[Hn];
  __shared__ float g2[512];
  __shared__ float heads[17];
  __shared__ float pred_s;
  const float* Wcol = Wh_d + j;
  REP32(WDECL)
  REP32(WLOAD)
  REP32(WPIN)
  float bhn = 0.f, wr0 = 0.f, wz0 = 0.f, wn0 = 0.f;
  if (j < Hn) {
    bhn = bhn_d[j];
    wr0 = Wi_d[j];          // Wi_d row 0: pred coefficient for r/z/n columns
    wz0 = Wi_d[128 + j];
    wn0 = Wi_d[256 + j];
    h[j] = (t0 == 0) ? 0.f : dec_h[(long)b * Hn + j];
  }
  asm volatile("" : "+v"(bhn), "+v"(wr0), "+v"(wz0), "+v"(wn0));
  if (j == 0) pred_s = (t0 == 0) ? 0.f : dec_pred[b];
  // head weights: 17 outputs x 16 threads, each thread 8 weights
  float hw[8] = {};
  const int o = j >> 4, g = j & 15;
  float hbias = 0.f;
  if (j < 272) {
#pragma unroll
    for (int u = 0; u < 8; ++u) {
      int k = g * 8 + u;
      float w;
      if (o == 0) w = W_shift[k];
      else if (o == 1) w = W_lsc[k];
      else if (o < 7) w = W_pi[k * 5 + (o - 2)];
      else if (o < 12) w = W_mu[k * 5 + (o - 7)];
      else w = W_ls[k * 5 + (o - 12)];
      hw[u] = w;
    }
    if (g == 0)
      hbias = (o == 0) ? b_shift[0] : (o == 1) ? b_lsc[0] : (o < 7) ? b_pi[o - 2]
              : (o < 12) ? b_mu[o - 7] : b_ls[o - 12];
  }
  asm volatile("" : "+v"(hw[0]), "+v"(hw[1]), "+v"(hw[2]), "+v"(hw[3]));
  asm volatile("" : "+v"(hw[4]), "+v"(hw[5]), "+v"(hw[6]), "+v"(hw[7]));
  asm volatile("" : "+v"(hbias));
  const u16* girow = gi_pre + (long)b * Tc * G3 + j;
  const float* erow = eps + (long)b * Tn;
  float e_cur = erow[t0];
  u16 gA = girow[0];
  u16 gB = girow[(Tc > 1) ? G3 : 0];
  __syncthreads();
  for (int tt = 0; tt < Tc; ++tt) {
    const int t = t0 + tt;
    const int tt2 = (tt + 2 < Tc) ? tt + 2 : Tc - 1;
    const int t1 = (t + 1 < Tn) ? t + 1 : Tn - 1;
    u16 gC = girow[(long)tt2 * G3];   // prefetch 2 steps ahead
    float e_next = erow[t1];
    float a0 = 0.f, a1 = 0.f, a2 = 0.f, a3 = 0.f;
    const float4* h4 = (const float4*)h;
    REP32(WFMA)
    float gh = (a0 + a1) + (a2 + a3);
    float gipre = h2f(gA);            // input-projection part WITHOUT pred term
    if (j < 256) g2[j] = gh + gipre;
    else { g2[j] = gh; g2[j + 128] = gipre; }
    __syncthreads();                                   // B1
    if (j < Hn) {
      float pred = pred_s;
      float r = sigm(fmaf(pred, wr0, g2[j]));
      float z = sigm(fmaf(pred, wz0, g2[128 + j]));
      float n = tanh_fast(fmaf(pred, wn0, g2[384 + j]) + r * (g2[256 + j] + bhn));
      float hn = (1.f - z) * n + z * h[j];
      h[j] = hn;
    }
    __syncthreads();                                   // B2
    if (j < 272) {
      const float4* hh = (const float4*)h;
      float4 v0 = hh[g * 2], v1 = hh[g * 2 + 1];
      float p = v0.x * hw[0] + v0.y * hw[1] + v0.z * hw[2] + v0.w * hw[3]
              + v1.x * hw[4] + v1.y * hw[5] + v1.z * hw[6] + v1.w * hw[7];
      p += __shfl_xor(p, 8, 16);
      p += __shfl_xor(p, 4, 16);
      p += __shfl_xor(p, 2, 16);
      p += __shfl_xor(p, 1, 16);
      if (g == 0) heads[o] = p + hbias;
    }
    __syncthreads();                                   // B3
    if (j < 8) {
      const float e = e_cur;
      const bool valid = j < 5;
      float pi_ = valid ? heads[2 + j] : -__builtin_inff();
      float mu_ = valid ? heads[7 + j] : 0.f;
      float ls_ = valid ? heads[12 + j] : 0.f;
      // log_softmax over K (8-lane padded)
      float m1 = pi_;
      m1 = fmaxf(m1, __shfl_xor(m1, 1, 8));
      m1 = fmaxf(m1, __shfl_xor(m1, 2, 8));
      m1 = fmaxf(m1, __shfl_xor(m1, 4, 8));
      float se = __expf(pi_ - m1);
      se += __shfl_xor(se, 1, 8);
      se += __shfl_xor(se, 2, 8);
      se += __shfl_xor(se, 4, 8);
      float lpi = pi_ - m1 - __logf(se);
      // logistic logcdf / logpdf at z
      float zz = (e - mu_) * __expf(-ls_);
      float az = fabsf(zz);
      float sp0 = log1pf(__expf(-az));           // log1p(e^{-|z|})
      float lcdf = fminf(zz, 0.f) - sp0;         // log_sigmoid(z)
      float lpdf = -az - 2.f * sp0 - ls_;        // -2*logaddexp(z/2,-z/2) - ls
      float aa = valid ? lpi + lcdf : -__builtin_inff();
      float bb2 = valid ? lpi + lpdf : -__builtin_inff();
      float ma = aa, mb = bb2;
      ma = fmaxf(ma, __shfl_xor(ma, 1, 8));
      ma = fmaxf(ma, __shfl_xor(ma, 2, 8));
      ma = fmaxf(ma, __shfl_xor(ma, 4, 8));
      mb = fmaxf(mb, __shfl_xor(mb, 1, 8));
      mb = fmaxf(mb, __shfl_xor(mb, 2, 8));
      mb = fmaxf(mb, __shfl_xor(mb, 4, 8));
      float sa = __expf(aa - ma);
      float sb = __expf(bb2 - mb);
      sa += __shfl_xor(sa, 1, 8);
      sa += __shfl_xor(sa, 2, 8);
      sa += __shfl_xor(sa, 4, 8);
      sb += __shfl_xor(sb, 1, 8);
      sb += __shfl_xor(sb, 2, 8);
      sb += __shfl_xor(sb, 4, 8);
      if (j == 0) {
        float lcm = ma + __logf(sa);
        float lpm = mb + __logf(sb);
        float lc = fminf(lcm, -1e-12f);
        float l1m = __logf(-expm1f(lc));
        float val = lc - l1m;
        float ljac = lpm - lc - l1m;
        float shiftv = heads[0], lsc = heads[1];
        float prednew = fmaf(val, __expf(lsc), shiftv);
        float sp = fmaxf(-e, 0.f) + log1pf(__expf(-fabsf(e)));  // softplus(-e)
        float logp = (-e - 2.f * sp) - lsc - ljac;
        out[(long)b * Tn + t] = logp;
        out[(long)Bn * Tn + (long)b * Tn + t] = prednew;
        pred_s = prednew;   // read by gates only after next B1 — no B4 needed
      }
    }
    gA = gB; gB = gC; e_cur = e_next;
    // no barrier here: matvec(t+1) touches only h (stable) and g2 (writers
    // passed B3; gate readers of step t finished before B2).
  }
  if (j < Hn) dec_h[(long)b * Hn + j] = h[j];
  __syncthreads();
  if (j == 0) dec_pred[b] = pred_s;
}

extern "C" void kernel_launch(void* const* d_in, const int* in_sizes, int n_in,
                              void* d_out, int out_size, void* d_ws, size_t ws_size,
                              hipStream_t stream) {
  // setup_inputs order: s(0,unused) x(1) eps(2) Wi_e(3) Wh_e(4) bi_e(5) bhn_e(6)
  // Wi_d(7) Wh_d(8) bi_d(9) bhn_d(10) W_shift(11) b_shift(12) W_lsc(13) b_lsc(14)
  // W_pi(15) b_pi(16) W_mu(17) b_mu(18) W_ls(19) b_ls(20)
  const float* x = (const float*)d_in[1];
  const float* eps = (const float*)d_in[2];
  const float* Wi_e = (const float*)d_in[3];
  const float* Wh_e = (const float*)d_in[4];
  const float* bi_e = (const float*)d_in[5];
  const float* bhn_e = (const float*)d_in[6];
  const float* Wi_d = (const float*)d_in[7];
  const float* Wh_d = (const float*)d_in[8];
  const float* bi_d = (const float*)d_in[9];
  const float* bhn_d = (const float*)d_in[10];
  const float* W_shift = (const float*)d_in[11];
  const float* b_shift = (const float*)d_in[12];
  const float* W_lsc = (const float*)d_in[13];
  const float* b_lsc = (const float*)d_in[14];
  const float* W_pi = (const float*)d_in[15];
  const float* b_pi = (const float*)d_in[16];
  const float* W_mu = (const float*)d_in[17];
  const float* b_mu = (const float*)d_in[18];
  const float* W_ls = (const float*)d_in[19];
  const float* b_ls = (const float*)d_in[20];
  float* out = (float*)d_out;

  // --- workspace layout: small persisted state + chunk buffers, sized to fit ---
  const size_t stateB = (size_t)(2 * Bn * Hn + Bn) * sizeof(float);
  const size_t stateAl = (stateB + 255) & ~(size_t)255;
  int Tc = Tn;
  while (Tc > 8) {
    size_t need = stateAl + (size_t)Bn * Tc * (Hn + G3) * 2;
    if (need <= ws_size) break;
    Tc >>= 1;
  }
  if (stateAl + (size_t)Bn * Tc * (Hn + G3) * 2 > ws_size) return;  // hopeless

  float* enc_h = (float*)d_ws;
  float* dec_h = enc_h + (size_t)Bn * Hn;
  float* dec_pred = dec_h + (size_t)Bn * Hn;
  u16* hx = (u16*)((char*)d_ws + stateAl);
  u16* gi = hx + (size_t)Bn * Tc * Hn;

  const dim3 gg((unsigned)(((size_t)Bn * Tc) / 64), G3 / 64);
  for (int t0 = 0; t0 < Tn; t0 += Tc) {
    enc_kernel<<<Bn, 384, 0, stream>>>(x, Wi_e, Wh_e, bi_e, bhn_e, hx, enc_h, t0, Tc);
    gemm_gi<<<gg, 256, 0, stream>>>(hx, Wi_d, bi_d, gi);
    dec_kernel<<<Bn, 384, 0, stream>>>(eps, Wi_d, Wh_d, bhn_d, W_shift, b_shift,
                                       W_lsc, b_lsc, W_pi, b_pi, W_mu, b_mu,
                                       W_ls, b_ls, gi, out, dec_h, dec_pred, t0, Tc);
  }
}

// Round 5
// 7056.239 us; speedup vs baseline: 1.9690x; 1.9690x over previous
//
#include <hip/hip_runtime.h>
#include <hip/hip_fp16.h>

#define Tn 4096
#define Bn 128
#define Hn 128
#define G3 384
#define NTH 448        // 7 waves: waves 0-5 matvec/gates, wave 6 heads+coupling
#define HWPAD 132      // head-weight LDS row stride (16B aligned, bank-staggered)

typedef unsigned short u16;
typedef unsigned int u32;

__device__ __forceinline__ float sigm(float v) { return 1.f / (1.f + __expf(-v)); }
__device__ __forceinline__ float tanh_fast(float v) {
  v = fminf(fmaxf(v, -15.f), 15.f);
  float e = __expf(-2.f * v);
  return (1.f - e) / (1.f + e);
}
__device__ __forceinline__ u16 f2h(float f) { return __half_as_ushort(__float2half(f)); }
__device__ __forceinline__ float h2f(u16 u) { return __half2float(__ushort_as_half(u)); }

#define REP32(M) M(0) M(1) M(2) M(3) M(4) M(5) M(6) M(7) M(8) M(9) M(10) M(11) \
  M(12) M(13) M(14) M(15) M(16) M(17) M(18) M(19) M(20) M(21) M(22) M(23) \
  M(24) M(25) M(26) M(27) M(28) M(29) M(30) M(31)
#define WDECL(i) float4 w##i;
#define WLOAD(i) w##i = make_float4(Wcol[(4*i+0)*G3], Wcol[(4*i+1)*G3], \
                                    Wcol[(4*i+2)*G3], Wcol[(4*i+3)*G3]);
#define WFMA(i) { float4 hv = h4[i]; \
  a0 = fmaf(hv.x, w##i.x, a0); a1 = fmaf(hv.y, w##i.y, a1); \
  a2 = fmaf(hv.z, w##i.z, a2); a3 = fmaf(hv.w, w##i.w, a3); }

// ================= combo: enc blocks (0..127) + dec blocks (128..255) ==========
__global__ __launch_bounds__(NTH, 1) void combo_kernel(
    const float* __restrict__ x, const float* __restrict__ Wi_e,
    const float* __restrict__ Wh_e, const float* __restrict__ bi_e,
    const float* __restrict__ bhn_e, u16* __restrict__ hx,
    float* __restrict__ enc_h,
    const float* __restrict__ eps, const float* __restrict__ Wi_d,
    const float* __restrict__ Wh_d, const float* __restrict__ bhn_d,
    const float* __restrict__ W_shift, const float* __restrict__ b_shift,
    const float* __restrict__ W_lsc, const float* __restrict__ b_lsc,
    const float* __restrict__ W_pi, const float* __restrict__ b_pi,
    const float* __restrict__ W_mu, const float* __restrict__ b_mu,
    const float* __restrict__ W_ls, const float* __restrict__ b_ls,
    const u16* __restrict__ gi_pre, float* __restrict__ out,
    float* __restrict__ dec_h, float* __restrict__ dec_pred,
    int enc_t0, int dec_t0, int Tc)
{
  const int j = threadIdx.x;
  __shared__ __align__(16) float h[Hn];
  __shared__ __align__(16) float g2[512];
  __shared__ __align__(16) float hwl[17 * HWPAD + 20];  // head weights + biases
  __shared__ float pred_s;
  const int bid = blockIdx.x;

  if (bid < Bn) {
    // ---------------------------- encoder role ----------------------------
    if (enc_t0 < 0) return;
    const int b = bid, t0 = enc_t0;
    const float* Wcol = Wh_e + (j < 384 ? j : 0);
    REP32(WDECL) REP32(WLOAD)
    float wie = 0.f, bie = 0.f, bhn = 0.f;
    if (j < 384) { wie = Wi_e[j]; bie = bi_e[j]; }
    if (j < Hn) {
      bhn = bhn_e[j];
      h[j] = (t0 == 0) ? 0.f : enc_h[(long)b * Hn + j];
    }
    __syncthreads();
    const float* xrow = x + (long)b * Tn;
    u16* hxrow = hx + (long)b * Tc * Hn;
    float xt = xrow[Tn - 1 - t0];
    for (int tt = 0; tt < Tc; ++tt) {
      const int t = t0 + tt;
      const int tnext = (t + 1 < Tn) ? (t + 1) : (Tn - 1);
      float xnext = xrow[Tn - 1 - tnext];
      if (j < 384) {
        float a0 = 0.f, a1 = 0.f, a2 = 0.f, a3 = 0.f;
        const float4* h4 = (const float4*)h;
        REP32(WFMA)
        float gh = (a0 + a1) + (a2 + a3);
        float gi = fmaf(xt, wie, bie);
        if (j < 256) g2[j] = gh + gi;
        else { g2[j] = gh; g2[j + 128] = gi; }
      }
      __syncthreads();
      if (j < Hn) {
        float r = sigm(g2[j]);
        float z = sigm(g2[128 + j]);
        float n = tanh_fast(g2[384 + j] + r * (g2[256 + j] + bhn));
        float hn = (1.f - z) * n + z * h[j];
        h[j] = hn;
        hxrow[(long)tt * Hn + j] = f2h(hn);
      }
      xt = xnext;
      __syncthreads();
    }
    if (j < Hn) enc_h[(long)b * Hn + j] = h[j];
  } else {
    // ---------------------------- decoder role ----------------------------
    if (dec_t0 < 0) return;
    const int b = bid - Bn, t0 = dec_t0;
    const float* Wcol = Wh_d + (j < 384 ? j : 0);
    REP32(WDECL) REP32(WLOAD)
    float bhn = 0.f, wr0 = 0.f, wz0 = 0.f, wn0 = 0.f;
    if (j < Hn) {
      bhn = bhn_d[j];
      wr0 = Wi_d[j];           // Wi_d row 0: pred coefficients
      wz0 = Wi_d[128 + j];
      wn0 = Wi_d[256 + j];
      h[j] = (t0 == 0) ? 0.f : dec_h[(long)b * Hn + j];
    }
    // stage head weights (17 x 128) + biases in LDS, bank-staggered rows
    for (int idx = j; idx < 17 * 128 + 17; idx += NTH) {
      if (idx < 17 * 128) {
        int o = idx >> 7, k = idx & 127;
        float w;
        if (o == 0) w = W_shift[k];
        else if (o == 1) w = W_lsc[k];
        else if (o < 7) w = W_pi[k * 5 + (o - 2)];
        else if (o < 12) w = W_mu[k * 5 + (o - 7)];
        else w = W_ls[k * 5 + (o - 12)];
        hwl[o * HWPAD + k] = w;
      } else {
        int o = idx - 17 * 128;
        hwl[17 * HWPAD + o] =
            (o == 0) ? b_shift[0] : (o == 1) ? b_lsc[0] : (o < 7) ? b_pi[o - 2]
            : (o < 12) ? b_mu[o - 7] : b_ls[o - 12];
      }
    }
    float predreg = (t0 == 0) ? 0.f : dec_pred[b];
    if (j == 384) pred_s = predreg;
    const u16* girow = gi_pre + (long)b * Tc * G3 + (j < 384 ? j : 0);
    const float* erow = eps + (long)b * Tn;
    u16 gA = 0, gB = 0;
    if (j < 384) { gA = girow[0]; gB = girow[G3]; }
    float e_cur = erow[t0];
    __syncthreads();
    const int lane = j - 384;            // wave-6 lane (valid when j>=384)
    const int ho = lane >> 1, hs = lane & 1;
    float* outlp = out + (long)b * Tn + t0;
    float* outpr = out + (long)Bn * Tn + (long)b * Tn + t0;
    // slot i: [waves0-5: matvec(i)] || [wave6: heads+coupling(i-1)] ; B1 ; gates(i) ; B2
    for (int i = 0; i <= Tc; ++i) {
      u16 gC = 0; float e_next = 0.f;
      if (j < 384 && i < Tc) {
        int ip = (i + 2 < Tc) ? i + 2 : Tc - 1;
        gC = girow[(long)ip * G3];       // prefetch 2 ahead
      }
      if (j >= 384 && i < Tc) e_next = erow[t0 + i];
      if (j < 384) {
        if (i < Tc) {
          float a0 = 0.f, a1 = 0.f, a2 = 0.f, a3 = 0.f;
          const float4* h4 = (const float4*)h;
          REP32(WFMA)
          float gh = (a0 + a1) + (a2 + a3);
          float gipre = h2f(gA);
          if (j < 256) g2[j] = gh + gipre;
          else { g2[j] = gh; g2[j + 128] = gipre; }
        }
      } else if (i >= 1) {
        // ---- heads for step i-1 (2 lanes per head: lane = 2*o + s) ----
        float p = 0.f;
        if (lane < 34) {
          const float4* hh = (const float4*)h;
          const float* wrow = &hwl[ho * HWPAD + hs * 64];
#pragma unroll
          for (int q = 0; q < 16; ++q) {
            float4 hv = hh[hs * 16 + q];
            float4 wv = *(const float4*)&wrow[4 * q];
            p = fmaf(hv.x, wv.x, p); p = fmaf(hv.y, wv.y, p);
            p = fmaf(hv.z, wv.z, p); p = fmaf(hv.w, wv.w, p);
          }
        }
        p += __shfl_xor(p, 1);           // combine the two half-dots
        float pb = p + hwl[17 * HWPAD + (lane < 34 ? ho : 0)];
        // redistribute to coupling lanes (octet lanes 0-7 use lj = lane&7)
        const int lj = lane & 7;
        float pi_ = __shfl(pb, 4 + 2 * lj);    // head 2+lj
        float mu_ = __shfl(pb, 14 + 2 * lj);   // head 7+lj
        float ls_ = __shfl(pb, 24 + 2 * lj);   // head 12+lj
        float shiftv = __shfl(pb, 0);          // head 0
        float lscv = __shfl(pb, 2);            // head 1
        // ---- linear-domain mixture-logistic coupling ----
        const bool valid = (lane < 5);
        const float e = e_cur;
        float wexp = valid ? __expf(pi_) : 0.f;
        float zz = (e - mu_) * __expf(-ls_);
        float u = __expf(-fabsf(zz));
        float d = 1.f / (1.f + u);
        float sigp = (zz >= 0.f) ? d : u * d;        // sigmoid(z)
        float sigq = (zz >= 0.f) ? u * d : d;        // sigmoid(-z)
        float pdfl = u * d * d * __expf(-ls_);       // logistic pdf
        float c = wexp * sigp, m = wexp * sigq, pp = wexp * pdfl, S = wexp;
        c += __shfl_xor(c, 1, 8); m += __shfl_xor(m, 1, 8);
        pp += __shfl_xor(pp, 1, 8); S += __shfl_xor(S, 1, 8);
        c += __shfl_xor(c, 2, 8); m += __shfl_xor(m, 2, 8);
        pp += __shfl_xor(pp, 2, 8); S += __shfl_xor(S, 2, 8);
        c += __shfl_xor(c, 4, 8); m += __shfl_xor(m, 4, 8);
        pp += __shfl_xor(pp, 4, 8); S += __shfl_xor(S, 4, 8);
        if (lane == 0) {
          float logc = __logf(c), logm = __logf(m);
          float val = logc - logm;                       // logit(CDF)
          float ljac = __logf(pp) + __logf(S) - logc - logm;
          float prednew = fmaf(val, __expf(lscv), shiftv);
          float sp = fmaxf(-e, 0.f) + log1pf(__expf(-fabsf(e)));  // softplus(-e)
          float logp = (-e - 2.f * sp) - lscv - ljac;
          outlp[i - 1] = logp;
          outpr[i - 1] = prednew;
          pred_s = prednew;
          predreg = prednew;
        }
      }
      __syncthreads();                                   // B1
      if (j < Hn && i < Tc) {
        float pred = pred_s;
        float r = sigm(fmaf(pred, wr0, g2[j]));
        float z = sigm(fmaf(pred, wz0, g2[128 + j]));
        float n = tanh_fast(fmaf(pred, wn0, g2[384 + j]) + r * (g2[256 + j] + bhn));
        h[j] = (1.f - z) * n + z * h[j];
      }
      __syncthreads();                                   // B2
      gA = gB; gB = gC; e_cur = e_next;
    }
    if (j < Hn) dec_h[(long)b * Hn + j] = h[j];
    if (j == 384) dec_pred[b] = predreg;
  }
}

// ------- GEMM: gi_pre[row,:] = hx[row,:] @ Wi_d[1:,:] + bi_d  (fp32 acc) -------
__global__ __launch_bounds__(256) void gemm_gi(
    const u16* __restrict__ A, const float* __restrict__ Wi_d,
    const float* __restrict__ bi_d, u16* __restrict__ C)
{
  __shared__ __align__(16) float As[16][64];  // [k][m]
  __shared__ __align__(16) float Ws[16][64];  // [k][n]
  const int tid = threadIdx.x;
  const long m0 = (long)blockIdx.x * 64;
  const int n0 = blockIdx.y * 64;
  const int tx = tid & 15, ty = tid >> 4;
  const int am = tid >> 2, ak = (tid & 3) * 4;
  const int wk = tid >> 4, wn = (tid & 15) * 4;
  float acc[4][4] = {};
  for (int k0 = 0; k0 < Hn; k0 += 16) {
    uint2 a2v = *(const uint2*)(A + (m0 + am) * Hn + k0 + ak);
    float4 w4 = *(const float4*)(Wi_d + (long)(1 + k0 + wk) * G3 + n0 + wn);
    __syncthreads();
    As[ak + 0][am] = h2f((u16)(a2v.x & 0xffffu));
    As[ak + 1][am] = h2f((u16)(a2v.x >> 16));
    As[ak + 2][am] = h2f((u16)(a2v.y & 0xffffu));
    As[ak + 3][am] = h2f((u16)(a2v.y >> 16));
    *(float4*)&Ws[wk][wn] = w4;
    __syncthreads();
#pragma unroll
    for (int kk = 0; kk < 16; ++kk) {
      float4 av = *(const float4*)&As[kk][ty * 4];
      float4 wv = *(const float4*)&Ws[kk][tx * 4];
      float ar[4] = {av.x, av.y, av.z, av.w};
      float wr[4] = {wv.x, wv.y, wv.z, wv.w};
#pragma unroll
      for (int i = 0; i < 4; ++i)
#pragma unroll
        for (int jj = 0; jj < 4; ++jj) acc[i][jj] = fmaf(ar[i], wr[jj], acc[i][jj]);
    }
  }
  const float4 bb = *(const float4*)(bi_d + n0 + tx * 4);
  const float br[4] = {bb.x, bb.y, bb.z, bb.w};
#pragma unroll
  for (int i = 0; i < 4; ++i) {
    long row = m0 + ty * 4 + i;
    u32 lo = (u32)f2h(acc[i][0] + br[0]) | ((u32)f2h(acc[i][1] + br[1]) << 16);
    u32 hi = (u32)f2h(acc[i][2] + br[2]) | ((u32)f2h(acc[i][3] + br[3]) << 16);
    uint2 o; o.x = lo; o.y = hi;
    *(uint2*)(C + row * G3 + n0 + tx * 4) = o;
  }
}

extern "C" void kernel_launch(void* const* d_in, const int* in_sizes, int n_in,
                              void* d_out, int out_size, void* d_ws, size_t ws_size,
                              hipStream_t stream) {
  // setup_inputs order: s(0,unused) x(1) eps(2) Wi_e(3) Wh_e(4) bi_e(5) bhn_e(6)
  // Wi_d(7) Wh_d(8) bi_d(9) bhn_d(10) W_shift(11) b_shift(12) W_lsc(13) b_lsc(14)
  // W_pi(15) b_pi(16) W_mu(17) b_mu(18) W_ls(19) b_ls(20)
  const float* x = (const float*)d_in[1];
  const float* eps = (const float*)d_in[2];
  const float* Wi_e = (const float*)d_in[3];
  const float* Wh_e = (const float*)d_in[4];
  const float* bi_e = (const float*)d_in[5];
  const float* bhn_e = (const float*)d_in[6];
  const float* Wi_d = (const float*)d_in[7];
  const float* Wh_d = (const float*)d_in[8];
  const float* bi_d = (const float*)d_in[9];
  const float* bhn_d = (const float*)d_in[10];
  const float* W_shift = (const float*)d_in[11];
  const float* b_shift = (const float*)d_in[12];
  const float* W_lsc = (const float*)d_in[13];
  const float* b_lsc = (const float*)d_in[14];
  const float* W_pi = (const float*)d_in[15];
  const float* b_pi = (const float*)d_in[16];
  const float* W_mu = (const float*)d_in[17];
  const float* b_mu = (const float*)d_in[18];
  const float* W_ls = (const float*)d_in[19];
  const float* b_ls = (const float*)d_in[20];
  float* out = (float*)d_out;

  const size_t stateB = (size_t)(2 * Bn * Hn + Bn) * sizeof(float);
  const size_t stateAl = (stateB + 255) & ~(size_t)255;
  int Tc = 512;  // chunk size: small enough to pipeline enc||dec, 8 chunks
  while (Tc > 8 && stateAl + (size_t)Bn * Tc * (Hn + G3) * 2 > ws_size) Tc >>= 1;
  if (stateAl + (size_t)Bn * Tc * (Hn + G3) * 2 > ws_size) return;

  float* enc_h = (float*)d_ws;
  float* dec_h = enc_h + (size_t)Bn * Hn;
  float* dec_pred = dec_h + (size_t)Bn * Hn;
  u16* hx = (u16*)((char*)d_ws + stateAl);
  u16* gi = hx + (size_t)Bn * Tc * Hn;

  const int Nc = Tn / Tc;
  const dim3 gg((unsigned)(((size_t)Bn * Tc) / 64), G3 / 64);
  // pipeline: combo(enc chunk k || dec chunk k-1), then gemm(k)
  for (int k = 0; k <= Nc; ++k) {
    int enc_t0 = (k < Nc) ? k * Tc : -1;
    int dec_t0 = (k >= 1) ? (k - 1) * Tc : -1;
    combo_kernel<<<2 * Bn, NTH, 0, stream>>>(
        x, Wi_e, Wh_e, bi_e, bhn_e, hx, enc_h,
        eps, Wi_d, Wh_d, bhn_d, W_shift, b_shift, W_lsc, b_lsc,
        W_pi, b_pi, W_mu, b_mu, W_ls, b_ls,
        gi, out, dec_h, dec_pred, enc_t0, dec_t0, Tc);
    if (k < Nc) gemm_gi<<<gg, 256, 0, stream>>>(hx, Wi_d, bi_d, gi);
  }
}

// Round 6
// 6817.251 us; speedup vs baseline: 2.0380x; 1.0351x over previous
//
#include <hip/hip_runtime.h>
#include <hip/hip_fp16.h>

#define Tn 4096
#define Bn 128
#define Hn 128
#define G3 384
#define NTH 448        // 7 waves: waves 0-5 matvec/gates, wave 6 heads+coupling
#define HWPAD 132      // head-weight LDS row stride (16B aligned, bank-staggered)

typedef unsigned short u16;
typedef unsigned int u32;

__device__ __forceinline__ float sigm(float v) { return 1.f / (1.f + __expf(-v)); }
__device__ __forceinline__ float tanh_fast(float v) {
  v = fminf(fmaxf(v, -15.f), 15.f);
  float e = __expf(-2.f * v);
  return (1.f - e) / (1.f + e);
}
__device__ __forceinline__ u16 f2h(float f) { return __half_as_ushort(__float2half(f)); }
__device__ __forceinline__ float h2f(u16 u) { return __half2float(__ushort_as_half(u)); }

#define REP32(M) M(0) M(1) M(2) M(3) M(4) M(5) M(6) M(7) M(8) M(9) M(10) M(11) \
  M(12) M(13) M(14) M(15) M(16) M(17) M(18) M(19) M(20) M(21) M(22) M(23) \
  M(24) M(25) M(26) M(27) M(28) M(29) M(30) M(31)
#define WDECL(i) float4 w##i;
#define WLOAD(i) w##i = make_float4(Wcol[(4*i+0)*G3], Wcol[(4*i+1)*G3], \
                                    Wcol[(4*i+2)*G3], Wcol[(4*i+3)*G3]);
// Loop-carried opaque pin: executed EVERY iteration, it redefines the values,
// so load-sinking/remat into the loop is illegal — true register residency.
#define WPIN(i) asm volatile("" : "+v"(w##i.x), "+v"(w##i.y), "+v"(w##i.z), "+v"(w##i.w));
#define WFMA(i) { float4 hv = h4[i]; \
  a0 = fmaf(hv.x, w##i.x, a0); a1 = fmaf(hv.y, w##i.y, a1); \
  a2 = fmaf(hv.z, w##i.z, a2); a3 = fmaf(hv.w, w##i.w, a3); }

// ================= combo: enc blocks (0..127) + dec blocks (128..255) ==========
__global__ __launch_bounds__(NTH, 1) void combo_kernel(
    const float* __restrict__ x, const float* __restrict__ Wi_e,
    const float* __restrict__ Wh_e, const float* __restrict__ bi_e,
    const float* __restrict__ bhn_e, u16* __restrict__ hx,
    float* __restrict__ enc_h,
    const float* __restrict__ eps, const float* __restrict__ Wi_d,
    const float* __restrict__ Wh_d, const float* __restrict__ bhn_d,
    const float* __restrict__ W_shift, const float* __restrict__ b_shift,
    const float* __restrict__ W_lsc, const float* __restrict__ b_lsc,
    const float* __restrict__ W_pi, const float* __restrict__ b_pi,
    const float* __restrict__ W_mu, const float* __restrict__ b_mu,
    const float* __restrict__ W_ls, const float* __restrict__ b_ls,
    const u16* __restrict__ gi_pre, float* __restrict__ out,
    float* __restrict__ dec_h, float* __restrict__ dec_pred,
    int enc_t0, int dec_t0, int Tc)
{
  const int j = threadIdx.x;
  __shared__ __align__(16) float h[Hn];
  __shared__ __align__(16) float g2[512];
  __shared__ __align__(16) float hwl[17 * HWPAD + 20];  // head weights + biases
  __shared__ float pred_s;
  const int bid = blockIdx.x;

  if (bid < Bn) {
    // ---------------------------- encoder role ----------------------------
    if (enc_t0 < 0) return;
    const int b = bid, t0 = enc_t0;
    const float* Wcol = Wh_e + (j < 384 ? j : 0);
    REP32(WDECL) REP32(WLOAD)
    float wie = 0.f, bie = 0.f, bhn = 0.f;
    if (j < 384) { wie = Wi_e[j]; bie = bi_e[j]; }
    if (j < Hn) {
      bhn = bhn_e[j];
      h[j] = (t0 == 0) ? 0.f : enc_h[(long)b * Hn + j];
    }
    __syncthreads();
    const float* xrow = x + (long)b * Tn;
    u16* hxrow = hx + (long)b * Tc * Hn;
    float xt = xrow[Tn - 1 - t0];
    for (int tt = 0; tt < Tc; ++tt) {
      REP32(WPIN)
      const int t = t0 + tt;
      const int tnext = (t + 1 < Tn) ? (t + 1) : (Tn - 1);
      float xnext = xrow[Tn - 1 - tnext];
      if (j < 384) {
        float a0 = 0.f, a1 = 0.f, a2 = 0.f, a3 = 0.f;
        const float4* h4 = (const float4*)h;
        REP32(WFMA)
        float gh = (a0 + a1) + (a2 + a3);
        float gi = fmaf(xt, wie, bie);
        if (j < 256) g2[j] = gh + gi;
        else { g2[j] = gh; g2[j + 128] = gi; }
      }
      __syncthreads();
      if (j < Hn) {
        float r = sigm(g2[j]);
        float z = sigm(g2[128 + j]);
        float n = tanh_fast(g2[384 + j] + r * (g2[256 + j] + bhn));
        float hn = (1.f - z) * n + z * h[j];
        h[j] = hn;
        hxrow[(long)tt * Hn + j] = f2h(hn);
      }
      xt = xnext;
      __syncthreads();
    }
    if (j < Hn) enc_h[(long)b * Hn + j] = h[j];
  } else {
    // ---------------------------- decoder role ----------------------------
    if (dec_t0 < 0) return;
    const int b = bid - Bn, t0 = dec_t0;
    const float* Wcol = Wh_d + (j < 384 ? j : 0);
    REP32(WDECL) REP32(WLOAD)
    float bhn = 0.f, wr0 = 0.f, wz0 = 0.f, wn0 = 0.f;
    if (j < Hn) {
      bhn = bhn_d[j];
      wr0 = Wi_d[j];           // Wi_d row 0: pred coefficients
      wz0 = Wi_d[128 + j];
      wn0 = Wi_d[256 + j];
      h[j] = (t0 == 0) ? 0.f : dec_h[(long)b * Hn + j];
    }
    // stage head weights (17 x 128) + biases in LDS, bank-staggered rows
    for (int idx = j; idx < 17 * 128 + 17; idx += NTH) {
      if (idx < 17 * 128) {
        int o = idx >> 7, k = idx & 127;
        float w;
        if (o == 0) w = W_shift[k];
        else if (o == 1) w = W_lsc[k];
        else if (o < 7) w = W_pi[k * 5 + (o - 2)];
        else if (o < 12) w = W_mu[k * 5 + (o - 7)];
        else w = W_ls[k * 5 + (o - 12)];
        hwl[o * HWPAD + k] = w;
      } else {
        int o = idx - 17 * 128;
        hwl[17 * HWPAD + o] =
            (o == 0) ? b_shift[0] : (o == 1) ? b_lsc[0] : (o < 7) ? b_pi[o - 2]
            : (o < 12) ? b_mu[o - 7] : b_ls[o - 12];
      }
    }
    float predreg = (t0 == 0) ? 0.f : dec_pred[b];
    if (j == 384) pred_s = predreg;
    const u16* girow = gi_pre + (long)b * Tc * G3 + (j < 384 ? j : 0);
    const float* erow = eps + (long)b * Tn;
    u16 gA = 0, gB = 0;
    if (j < 384) { gA = girow[0]; gB = girow[G3]; }
    float e_cur = erow[t0];
    __syncthreads();
    const int lane = j - 384;            // wave-6 lane (valid when j>=384)
    const int ho = lane >> 1, hs = lane & 1;
    float* outlp = out + (long)b * Tn + t0;
    float* outpr = out + (long)Bn * Tn + (long)b * Tn + t0;
    // slot i: [waves0-5: matvec(i)] || [wave6: heads+coupling(i-1)] ; B1 ; gates(i) ; B2
    for (int i = 0; i <= Tc; ++i) {
      u16 gC = 0; float e_next = 0.f;
      if (j < 384 && i < Tc) {
        int ip = (i + 2 < Tc) ? i + 2 : Tc - 1;
        gC = girow[(long)ip * G3];       // prefetch 2 ahead
      }
      if (j >= 384 && i < Tc) e_next = erow[t0 + i];
      if (j < 384) {
        REP32(WPIN)
        if (i < Tc) {
          float a0 = 0.f, a1 = 0.f, a2 = 0.f, a3 = 0.f;
          const float4* h4 = (const float4*)h;
          REP32(WFMA)
          float gh = (a0 + a1) + (a2 + a3);
          float gipre = h2f(gA);
          if (j < 256) g2[j] = gh + gipre;
          else { g2[j] = gh; g2[j + 128] = gipre; }
        }
      } else if (i >= 1) {
        // ---- heads for step i-1 (2 lanes per head: lane = 2*o + s) ----
        float p = 0.f;
        if (lane < 34) {
          const float4* hh = (const float4*)h;
          const float* wrow = &hwl[ho * HWPAD + hs * 64];
#pragma unroll
          for (int q = 0; q < 16; ++q) {
            float4 hv = hh[hs * 16 + q];
            float4 wv = *(const float4*)&wrow[4 * q];
            p = fmaf(hv.x, wv.x, p); p = fmaf(hv.y, wv.y, p);
            p = fmaf(hv.z, wv.z, p); p = fmaf(hv.w, wv.w, p);
          }
        }
        p += __shfl_xor(p, 1);           // combine the two half-dots
        float pb = p + hwl[17 * HWPAD + (lane < 34 ? ho : 0)];
        // redistribute to coupling lanes (octet lanes 0-7 use lj = lane&7)
        const int lj = lane & 7;
        float pi_ = __shfl(pb, 4 + 2 * lj);    // head 2+lj
        float mu_ = __shfl(pb, 14 + 2 * lj);   // head 7+lj
        float ls_ = __shfl(pb, 24 + 2 * lj);   // head 12+lj
        float shiftv = __shfl(pb, 0);          // head 0
        float lscv = __shfl(pb, 2);            // head 1
        // ---- linear-domain mixture-logistic coupling ----
        const bool valid = (lane < 5);
        const float e = e_cur;
        float wexp = valid ? __expf(pi_) : 0.f;
        float zz = (e - mu_) * __expf(-ls_);
        float u = __expf(-fabsf(zz));
        float d = 1.f / (1.f + u);
        float sigp = (zz >= 0.f) ? d : u * d;        // sigmoid(z)
        float sigq = (zz >= 0.f) ? u * d : d;        // sigmoid(-z)
        float pdfl = u * d * d * __expf(-ls_);       // logistic pdf
        float c = wexp * sigp, m = wexp * sigq, pp = wexp * pdfl, S = wexp;
        c += __shfl_xor(c, 1, 8); m += __shfl_xor(m, 1, 8);
        pp += __shfl_xor(pp, 1, 8); S += __shfl_xor(S, 1, 8);
        c += __shfl_xor(c, 2, 8); m += __shfl_xor(m, 2, 8);
        pp += __shfl_xor(pp, 2, 8); S += __shfl_xor(S, 2, 8);
        c += __shfl_xor(c, 4, 8); m += __shfl_xor(m, 4, 8);
        pp += __shfl_xor(pp, 4, 8); S += __shfl_xor(S, 4, 8);
        if (lane == 0) {
          float logc = __logf(c), logm = __logf(m);
          float val = logc - logm;                       // logit(CDF)
          float ljac = __logf(pp) + __logf(S) - logc - logm;
          float prednew = fmaf(val, __expf(lscv), shiftv);
          float sp = fmaxf(-e, 0.f) + log1pf(__expf(-fabsf(e)));  // softplus(-e)
          float logp = (-e - 2.f * sp) - lscv - ljac;
          outlp[i - 1] = logp;
          outpr[i - 1] = prednew;
          pred_s = prednew;
          predreg = prednew;
        }
      }
      __syncthreads();                                   // B1
      if (j < Hn && i < Tc) {
        float pred = pred_s;
        float r = sigm(fmaf(pred, wr0, g2[j]));
        float z = sigm(fmaf(pred, wz0, g2[128 + j]));
        float n = tanh_fast(fmaf(pred, wn0, g2[384 + j]) + r * (g2[256 + j] + bhn));
        h[j] = (1.f - z) * n + z * h[j];
      }
      __syncthreads();                                   // B2
      gA = gB; gB = gC; e_cur = e_next;
    }
    if (j < Hn) dec_h[(long)b * Hn + j] = h[j];
    if (j == 384) dec_pred[b] = predreg;
  }
}

// ------- GEMM: gi_pre[row,:] = hx[row,:] @ Wi_d[1:,:] + bi_d  (fp32 acc) -------
__global__ __launch_bounds__(256) void gemm_gi(
    const u16* __restrict__ A, const float* __restrict__ Wi_d,
    const float* __restrict__ bi_d, u16* __restrict__ C)
{
  __shared__ __align__(16) float As[16][64];  // [k][m]
  __shared__ __align__(16) float Ws[16][64];  // [k][n]
  const int tid = threadIdx.x;
  const long m0 = (long)blockIdx.x * 64;
  const int n0 = blockIdx.y * 64;
  const int tx = tid & 15, ty = tid >> 4;
  const int am = tid >> 2, ak = (tid & 3) * 4;
  const int wk = tid >> 4, wn = (tid & 15) * 4;
  float acc[4][4] = {};
  for (int k0 = 0; k0 < Hn; k0 += 16) {
    uint2 a2v = *(const uint2*)(A + (m0 + am) * Hn + k0 + ak);
    float4 w4 = *(const float4*)(Wi_d + (long)(1 + k0 + wk) * G3 + n0 + wn);
    __syncthreads();
    As[ak + 0][am] = h2f((u16)(a2v.x & 0xffffu));
    As[ak + 1][am] = h2f((u16)(a2v.x >> 16));
    As[ak + 2][am] = h2f((u16)(a2v.y & 0xffffu));
    As[ak + 3][am] = h2f((u16)(a2v.y >> 16));
    *(float4*)&Ws[wk][wn] = w4;
    __syncthreads();
#pragma unroll
    for (int kk = 0; kk < 16; ++kk) {
      float4 av = *(const float4*)&As[kk][ty * 4];
      float4 wv = *(const float4*)&Ws[kk][tx * 4];
      float ar[4] = {av.x, av.y, av.z, av.w};
      float wr[4] = {wv.x, wv.y, wv.z, wv.w};
#pragma unroll
      for (int i = 0; i < 4; ++i)
#pragma unroll
        for (int jj = 0; jj < 4; ++jj) acc[i][jj] = fmaf(ar[i], wr[jj], acc[i][jj]);
    }
  }
  const float4 bb = *(const float4*)(bi_d + n0 + tx * 4);
  const float br[4] = {bb.x, bb.y, bb.z, bb.w};
#pragma unroll
  for (int i = 0; i < 4; ++i) {
    long row = m0 + ty * 4 + i;
    u32 lo = (u32)f2h(acc[i][0] + br[0]) | ((u32)f2h(acc[i][1] + br[1]) << 16);
    u32 hi = (u32)f2h(acc[i][2] + br[2]) | ((u32)f2h(acc[i][3] + br[3]) << 16);
    uint2 o; o.x = lo; o.y = hi;
    *(uint2*)(C + row * G3 + n0 + tx * 4) = o;
  }
}

extern "C" void kernel_launch(void* const* d_in, const int* in_sizes, int n_in,
                              void* d_out, int out_size, void* d_ws, size_t ws_size,
                              hipStream_t stream) {
  // setup_inputs order: s(0,unused) x(1) eps(2) Wi_e(3) Wh_e(4) bi_e(5) bhn_e(6)
  // Wi_d(7) Wh_d(8) bi_d(9) bhn_d(10) W_shift(11) b_shift(12) W_lsc(13) b_lsc(14)
  // W_pi(15) b_pi(16) W_mu(17) b_mu(18) W_ls(19) b_ls(20)
  const float* x = (const float*)d_in[1];
  const float* eps = (const float*)d_in[2];
  const float* Wi_e = (const float*)d_in[3];
  const float* Wh_e = (const float*)d_in[4];
  const float* bi_e = (const float*)d_in[5];
  const float* bhn_e = (const float*)d_in[6];
  const float* Wi_d = (const float*)d_in[7];
  const float* Wh_d = (const float*)d_in[8];
  const float* bi_d = (const float*)d_in[9];
  const float* bhn_d = (const float*)d_in[10];
  const float* W_shift = (const float*)d_in[11];
  const float* b_shift = (const float*)d_in[12];
  const float* W_lsc = (const float*)d_in[13];
  const float* b_lsc = (const float*)d_in[14];
  const float* W_pi = (const float*)d_in[15];
  const float* b_pi = (const float*)d_in[16];
  const float* W_mu = (const float*)d_in[17];
  const float* b_mu = (const float*)d_in[18];
  const float* W_ls = (const float*)d_in[19];
  const float* b_ls = (const float*)d_in[20];
  float* out = (float*)d_out;

  const size_t stateB = (size_t)(2 * Bn * Hn + Bn) * sizeof(float);
  const size_t stateAl = (stateB + 255) & ~(size_t)255;
  int Tc = 512;  // chunk size: small enough to pipeline enc||dec, 8 chunks
  while (Tc > 8 && stateAl + (size_t)Bn * Tc * (Hn + G3) * 2 > ws_size) Tc >>= 1;
  if (stateAl + (size_t)Bn * Tc * (Hn + G3) * 2 > ws_size) return;

  float* enc_h = (float*)d_ws;
  float* dec_h = enc_h + (size_t)Bn * Hn;
  float* dec_pred = dec_h + (size_t)Bn * Hn;
  u16* hx = (u16*)((char*)d_ws + stateAl);
  u16* gi = hx + (size_t)Bn * Tc * Hn;

  const int Nc = Tn / Tc;
  const dim3 gg((unsigned)(((size_t)Bn * Tc) / 64), G3 / 64);
  // pipeline: combo(enc chunk k || dec chunk k-1), then gemm(k)
  for (int k = 0; k <= Nc; ++k) {
    int enc_t0 = (k < Nc) ? k * Tc : -1;
    int dec_t0 = (k >= 1) ? (k - 1) * Tc : -1;
    combo_kernel<<<2 * Bn, NTH, 0, stream>>>(
        x, Wi_e, Wh_e, bi_e, bhn_e, hx, enc_h,
        eps, Wi_d, Wh_d, bhn_d, W_shift, b_shift, W_lsc, b_lsc,
        W_pi, b_pi, W_mu, b_mu, W_ls, b_ls,
        gi, out, dec_h, dec_pred, enc_t0, dec_t0, Tc);
    if (k < Nc) gemm_gi<<<gg, 256, 0, stream>>>(hx, Wi_d, bi_d, gi);
  }
}